// Round 17
// baseline (201.063 us; speedup 1.0000x reference)
//
#include <hip/hip_runtime.h>
#include <hip/hip_fp16.h>

#define DD 64
#define NPB 64       // nodes per block in sage_layer (512 threads, 8 lanes/node)
#define EPC 8192     // edges per chunk in binning
#define BK_SHIFT 8   // 256 nodes per bucket
#define BNODES 256
#define SCHUNK 1024  // elements per scan block
#define APAD 136     // halves per sA row: 128 + 8 pad

typedef _Float16 half8 __attribute__((ext_vector_type(8)));
typedef float f32x4 __attribute__((ext_vector_type(4)));

union U8  { uint2 u; __half2 h[2]; };
union U16 { uint4 u; __half2 h[4]; };

// ---- fp32 -> fp16 row conversion (8 elems/thread) ----
__global__ __launch_bounds__(256) void f32_to_f16_kernel(const float* __restrict__ in,
                                                         __half* __restrict__ out, int n8) {
    int i = blockIdx.x * blockDim.x + threadIdx.x;
    if (i < n8) {
        const float4* p = reinterpret_cast<const float4*>(in + (size_t)i * 8);
        float4 a = p[0], b = p[1];
        __half2* q = reinterpret_cast<__half2*>(out + (size_t)i * 8);
        q[0] = __floats2half2_rn(a.x, a.y);
        q[1] = __floats2half2_rn(a.z, a.w);
        q[2] = __floats2half2_rn(b.x, b.y);
        q[3] = __floats2half2_rn(b.z, b.w);
    }
}

// ---- build MFMA B-fragments in fragment order, fp16 ----
// Layer stride = 4*4*64 fragments = 8192 halves.
// Wswz[L][kt][nt][lane][i]: k = kt*32 + 8*(lane>>4) + i, n = nt*16 + (lane&15)
__global__ __launch_bounds__(256) void wswz_kernel(const float* __restrict__ Wl,
                                                   const float* __restrict__ Wr,
                                                   __half* __restrict__ Wswz, int nlayer) {
    int idx = blockIdx.x * 256 + threadIdx.x;   // (L,kt,nt,lane)
    int total = nlayer * 4 * 4 * 64;
    if (idx >= total) return;
    int lane = idx & 63;
    int nt   = (idx >> 6) & 3;
    int kt   = (idx >> 8) & 3;
    int L    = idx >> 10;
    int n     = nt * 16 + (lane & 15);
    int kbase = kt * 32 + 8 * (lane >> 4);
    __half* o = Wswz + (size_t)idx * 8;
#pragma unroll
    for (int i = 0; i < 8; ++i) {
        int k = kbase + i;
        float v = (k < 64) ? Wl[(size_t)L * 4096 + (size_t)k * 64 + n]
                           : Wr[(size_t)L * 4096 + (size_t)(k - 64) * 64 + n];
        o[i] = __float2half(v);
    }
}

// ---- binned CSR build (unchanged) ----
__global__ __launch_bounds__(256) void binA_kernel(const int* __restrict__ dst, int e, int nc,
                                                   int* __restrict__ histT, int nbuck) {
    __shared__ int h[512];
    int tid = threadIdx.x, c = blockIdx.x;
    for (int i = tid; i < nbuck; i += 256) h[i] = 0;
    __syncthreads();
    int base = c * EPC;
#pragma unroll
    for (int j = 0; j < EPC / 256; ++j) {
        int i = base + j * 256 + tid;
        if (i < e) atomicAdd(&h[dst[i] >> BK_SHIFT], 1);
    }
    __syncthreads();
    for (int b = tid; b < nbuck; b += 256) histT[b * nc + c] = h[b];
}

__global__ __launch_bounds__(256) void scan_part_kernel(const int* __restrict__ data, int tot,
                                                        int* __restrict__ blocksum) {
    __shared__ int red[256];
    int tid = threadIdx.x;
    int base = blockIdx.x * SCHUNK + tid * 4;
    int s = 0;
#pragma unroll
    for (int j = 0; j < 4; ++j) {
        int i = base + j;
        if (i < tot) s += data[i];
    }
    red[tid] = s;
    __syncthreads();
    for (int off = 128; off > 0; off >>= 1) {
        if (tid < off) red[tid] += red[tid + off];
        __syncthreads();
    }
    if (tid == 0) blocksum[blockIdx.x] = red[0];
}

__global__ __launch_bounds__(1024) void scan_mid_kernel(int* __restrict__ blocksum, int nb) {
    __shared__ int sc[1024];
    int tid = threadIdx.x;
    int v = (tid < nb) ? blocksum[tid] : 0;
    sc[tid] = v;
    __syncthreads();
    for (int off = 1; off < 1024; off <<= 1) {
        int t = (tid >= off) ? sc[tid - off] : 0;
        __syncthreads();
        sc[tid] += t;
        __syncthreads();
    }
    if (tid < nb) blocksum[tid] = sc[tid] - v;   // exclusive
}

__global__ __launch_bounds__(256) void scan_write_kernel(int* __restrict__ data, int tot,
                                                         const int* __restrict__ blockoff) {
    __shared__ int sc[256];
    int tid = threadIdx.x;
    int base = blockIdx.x * SCHUNK + tid * 4;
    int e0 = 0, e1 = 0, e2 = 0, e3 = 0;
    if (base + 0 < tot) e0 = data[base + 0];
    if (base + 1 < tot) e1 = data[base + 1];
    if (base + 2 < tot) e2 = data[base + 2];
    if (base + 3 < tot) e3 = data[base + 3];
    int s = e0 + e1 + e2 + e3;
    sc[tid] = s;
    __syncthreads();
    for (int off = 1; off < 256; off <<= 1) {
        int t = (tid >= off) ? sc[tid - off] : 0;
        __syncthreads();
        sc[tid] += t;
        __syncthreads();
    }
    int run = blockoff[blockIdx.x] + sc[tid] - s;
    if (base + 0 < tot) data[base + 0] = run;
    if (base + 1 < tot) data[base + 1] = run + e0;
    if (base + 2 < tot) data[base + 2] = run + e0 + e1;
    if (base + 3 < tot) data[base + 3] = run + e0 + e1 + e2;
}

__global__ __launch_bounds__(256) void binB_kernel(const int* __restrict__ src, const int* __restrict__ dst,
                                                   int e, int nc, const int* __restrict__ offT,
                                                   int nbuck, int* __restrict__ binned) {
    __shared__ int cur[512];
    int tid = threadIdx.x, c = blockIdx.x;
    for (int b = tid; b < nbuck; b += 256) cur[b] = offT[b * nc + c];
    __syncthreads();
    int base = c * EPC;
#pragma unroll
    for (int j = 0; j < EPC / 256; ++j) {
        int i = base + j * 256 + tid;
        if (i < e) {
            int d = dst[i];
            int p = atomicAdd(&cur[d >> BK_SHIFT], 1);
            binned[p] = (unsigned)(d & (BNODES - 1)) << 24 | (unsigned)src[i];
        }
    }
}

__global__ __launch_bounds__(BNODES) void place_kernel(const int* __restrict__ binned,
                                                       const int* __restrict__ offT, int nc,
                                                       int nbuck, int e, int n,
                                                       int* __restrict__ rowp, int* __restrict__ esrc) {
    __shared__ int deg[BNODES];
    __shared__ int sc[BNODES];
    int tid = threadIdx.x, b = blockIdx.x;
    int node0 = b << BK_SHIFT;
    int base = offT[b * nc];
    int end  = (b + 1 < nbuck) ? offT[(b + 1) * nc] : e;
    deg[tid] = 0;
    __syncthreads();
    for (int i = base + tid; i < end; i += BNODES)
        atomicAdd(&deg[(unsigned)binned[i] >> 24], 1);
    __syncthreads();
    int v = deg[tid];
    sc[tid] = v;
    __syncthreads();
    for (int off = 1; off < BNODES; off <<= 1) {
        int t = (tid >= off) ? sc[tid - off] : 0;
        __syncthreads();
        sc[tid] += t;
        __syncthreads();
    }
    int excl = sc[tid] - v;
    int node = node0 + tid;
    if (node < n) rowp[node] = base + excl;
    if (b == 0 && tid == 0) rowp[n] = e;
    deg[tid] = base + excl;   // reuse as cursor
    __syncthreads();
    for (int i = base + tid; i < end; i += BNODES) {
        int p = binned[i];
        int pos = atomicAdd(&deg[(unsigned)p >> 24], 1);
        esrc[pos] = p & 0xFFFFFF;
    }
}

// Fused layer: fp16 gather (8 lanes/node, 16B/lane, 8-deep MLP) -> sA[64][136],
// then MFMA combine: 8 waves x 2 m-tiles x 4 nt-tiles over the 64-node block.
__global__ __launch_bounds__(512) void sage_layer_kernel(
    const __half* __restrict__ hin16, const float* __restrict__ self32,
    const int* __restrict__ rowp, const int* __restrict__ esrc,
    const __half* __restrict__ Bfrag,     // [4kt][4nt][64][8] fp16
    const float* __restrict__ bias,
    float* __restrict__ out32, __half* __restrict__ out16,
    int n, int relu)
{
    __shared__ _Float16 sA[NPB][APAD];    // 17.4 KB

    int tid = threadIdx.x;
    int grp = tid >> 3;      // node within block (0..63)
    int l   = tid & 7;       // 16B slice (0..7)
    int node = blockIdx.x * NPB + grp;

    if (node < n) {
        // self row -> sA[grp][64 + 8l ..]
        if (self32) {
            const float4* p = reinterpret_cast<const float4*>(self32 + (size_t)node * DD + l * 8);
            float4 a = p[0], b = p[1];
            U16 pk;
            pk.h[0] = __floats2half2_rn(a.x, a.y);
            pk.h[1] = __floats2half2_rn(a.z, a.w);
            pk.h[2] = __floats2half2_rn(b.x, b.y);
            pk.h[3] = __floats2half2_rn(b.z, b.w);
            *reinterpret_cast<uint4*>(&sA[grp][64 + 8 * l]) = pk.u;
        } else {
            uint4 v = *reinterpret_cast<const uint4*>(hin16 + (size_t)node * DD + l * 8);
            *reinterpret_cast<uint4*>(&sA[grp][64 + 8 * l]) = v;
        }

        // mean-aggregate neighbors: 16B/lane, 8-deep MLP, fp32 accumulate
        int beg = rowp[node], end = rowp[node + 1];
        float a0 = 0, a1 = 0, a2 = 0, a3 = 0, a4 = 0, a5 = 0, a6 = 0, a7 = 0;
#define ACC8(V) { float2 f0 = __half22float2(V.h[0]), f1 = __half22float2(V.h[1]); \
                  float2 f2 = __half22float2(V.h[2]), f3 = __half22float2(V.h[3]); \
                  a0 += f0.x; a1 += f0.y; a2 += f1.x; a3 += f1.y; \
                  a4 += f2.x; a5 += f2.y; a6 += f3.x; a7 += f3.y; }
        int t = beg;
        for (; t + 8 <= end; t += 8) {
            int s0 = esrc[t + 0], s1 = esrc[t + 1], s2 = esrc[t + 2], s3 = esrc[t + 3];
            int s4 = esrc[t + 4], s5 = esrc[t + 5], s6 = esrc[t + 6], s7 = esrc[t + 7];
            U16 v0, v1, v2, v3, v4, v5, v6, v7;
            v0.u = *reinterpret_cast<const uint4*>(hin16 + (size_t)s0 * DD + l * 8);
            v1.u = *reinterpret_cast<const uint4*>(hin16 + (size_t)s1 * DD + l * 8);
            v2.u = *reinterpret_cast<const uint4*>(hin16 + (size_t)s2 * DD + l * 8);
            v3.u = *reinterpret_cast<const uint4*>(hin16 + (size_t)s3 * DD + l * 8);
            v4.u = *reinterpret_cast<const uint4*>(hin16 + (size_t)s4 * DD + l * 8);
            v5.u = *reinterpret_cast<const uint4*>(hin16 + (size_t)s5 * DD + l * 8);
            v6.u = *reinterpret_cast<const uint4*>(hin16 + (size_t)s6 * DD + l * 8);
            v7.u = *reinterpret_cast<const uint4*>(hin16 + (size_t)s7 * DD + l * 8);
            ACC8(v0); ACC8(v1); ACC8(v2); ACC8(v3);
            ACC8(v4); ACC8(v5); ACC8(v6); ACC8(v7);
        }
        if (t + 4 <= end) {
            int s0 = esrc[t + 0], s1 = esrc[t + 1], s2 = esrc[t + 2], s3 = esrc[t + 3];
            U16 v0, v1, v2, v3;
            v0.u = *reinterpret_cast<const uint4*>(hin16 + (size_t)s0 * DD + l * 8);
            v1.u = *reinterpret_cast<const uint4*>(hin16 + (size_t)s1 * DD + l * 8);
            v2.u = *reinterpret_cast<const uint4*>(hin16 + (size_t)s2 * DD + l * 8);
            v3.u = *reinterpret_cast<const uint4*>(hin16 + (size_t)s3 * DD + l * 8);
            ACC8(v0); ACC8(v1); ACC8(v2); ACC8(v3);
            t += 4;
        }
        for (; t < end; ++t) {
            int s = esrc[t];
            U16 v; v.u = *reinterpret_cast<const uint4*>(hin16 + (size_t)s * DD + l * 8);
            ACC8(v);
        }
#undef ACC8
        float inv = 1.0f / fmaxf((float)(end - beg), 1.0f);
        U16 pk;
        pk.h[0] = __floats2half2_rn(a0 * inv, a1 * inv);
        pk.h[1] = __floats2half2_rn(a2 * inv, a3 * inv);
        pk.h[2] = __floats2half2_rn(a4 * inv, a5 * inv);
        pk.h[3] = __floats2half2_rn(a6 * inv, a7 * inv);
        *reinterpret_cast<uint4*>(&sA[grp][8 * l]) = pk.u;
    }
    __syncthreads();

    // MFMA combine: wave handles nt = wave&3, m-tiles {2*(wave>>2), 2*(wave>>2)+1}
    int wave = tid >> 6;
    int lane = tid & 63;
    int nt   = wave & 3;
    int mt0  = (wave >> 2) * 2;
    const half8* bfr = reinterpret_cast<const half8*>(Bfrag);
    half8 bf[4];
#pragma unroll
    for (int kt = 0; kt < 4; ++kt) bf[kt] = bfr[(kt * 4 + nt) * 64 + lane];
    int col = nt * 16 + (lane & 15);
    float bv = bias[col];
#pragma unroll
    for (int i = 0; i < 2; ++i) {
        int mtile = mt0 + i;
        int arow  = mtile * 16 + (lane & 15);
        f32x4 acc = {0.f, 0.f, 0.f, 0.f};
#pragma unroll
        for (int kt = 0; kt < 4; ++kt) {
            half8 a = *reinterpret_cast<const half8*>(&sA[arow][kt * 32 + 8 * (lane >> 4)]);
            acc = __builtin_amdgcn_mfma_f32_16x16x32_f16(a, bf[kt], acc, 0, 0, 0);
        }
        int rbase = blockIdx.x * NPB + mtile * 16 + (lane >> 4) * 4;
#pragma unroll
        for (int j = 0; j < 4; ++j) {
            int r = rbase + j;
            if (r < n) {
                float o = acc[j] + bv;
                if (relu) o = fmaxf(o, 0.f);
                if (out32) out32[(size_t)r * DD + col] = o;
                if (out16) out16[(size_t)r * DD + col] = __float2half(o);
            }
        }
    }
}

extern "C" void kernel_launch(void* const* d_in, const int* in_sizes, int n_in,
                              void* d_out, int out_size, void* d_ws, size_t ws_size,
                              hipStream_t stream) {
    (void)n_in; (void)out_size; (void)ws_size;
    const float* x  = (const float*)d_in[0];
    const int*   ei = (const int*)d_in[1];
    const float* Wl = (const float*)d_in[2];
    const float* Wr = (const float*)d_in[3];
    const float* bb = (const float*)d_in[4];
    float* out = (float*)d_out;

    int n = in_sizes[0] / DD;   // 100000
    int e = in_sizes[1] / 2;    // 1600000
    const int* src = ei;
    const int* dst = ei + e;

    int nc    = (e + EPC - 1) / EPC;          // 196
    int nbuck = (n + BNODES - 1) >> BK_SHIFT; // 391
    int tot   = nbuck * nc;
    int nsb   = (tot + SCHUNK - 1) / SCHUNK;

    char* cur = (char*)d_ws;
    auto alloc = [&](size_t bytes) -> void* {
        void* p = (void*)cur;
        cur += (bytes + 255) & ~(size_t)255;
        return p;
    };
    int*    histT  = (int*)alloc((size_t)tot * 4);
    int*    bsum   = (int*)alloc(1024 * 4);
    int*    binned = (int*)alloc((size_t)e * 4);
    int*    rowp   = (int*)alloc(((size_t)n + 1) * 4);
    int*    esrc   = (int*)alloc((size_t)e * 4);
    __half* x16    = (__half*)alloc((size_t)n * DD * 2);
    __half* hA16   = (__half*)alloc((size_t)n * DD * 2);
    __half* hB16   = (__half*)alloc((size_t)n * DD * 2);
    // 3 layers x (4kt x 4nt x 64 lanes x 8 halves) = 3 x 8192 halves (16 KB/layer)
    __half* Wswz   = (__half*)alloc((size_t)3 * 8192 * 2);

    int n8 = n * DD / 8;
    f32_to_f16_kernel<<<(n8 + 255) / 256, 256, 0, stream>>>(x, x16, n8);
    wswz_kernel<<<(3 * 4 * 4 * 64 + 255) / 256, 256, 0, stream>>>(Wl, Wr, Wswz, 3);

    binA_kernel<<<nc, 256, 0, stream>>>(dst, e, nc, histT, nbuck);
    scan_part_kernel<<<nsb, 256, 0, stream>>>(histT, tot, bsum);
    scan_mid_kernel<<<1, 1024, 0, stream>>>(bsum, nsb);
    scan_write_kernel<<<nsb, 256, 0, stream>>>(histT, tot, bsum);
    binB_kernel<<<nc, 256, 0, stream>>>(src, dst, e, nc, histT, nbuck, binned);
    place_kernel<<<nbuck, BNODES, 0, stream>>>(binned, histT, nc, nbuck, e, n, rowp, esrc);

    int lb = (n + NPB - 1) / NPB;
    sage_layer_kernel<<<lb, 512, 0, stream>>>(x16,  x,       rowp, esrc, Wswz,         bb,          nullptr, hA16, n, 1);
    sage_layer_kernel<<<lb, 512, 0, stream>>>(hA16, nullptr, rowp, esrc, Wswz + 8192,  bb + DD,     nullptr, hB16, n, 1);
    sage_layer_kernel<<<lb, 512, 0, stream>>>(hB16, nullptr, rowp, esrc, Wswz + 16384, bb + 2 * DD, out,     nullptr, n, 0);
}

// Round 18
// 185.409 us; speedup vs baseline: 1.0844x; 1.0844x over previous
//
#include <hip/hip_runtime.h>
#include <hip/hip_fp16.h>

#define DD 64
#define NPB 32       // nodes per block in sage_layer (512 threads, 16 lanes/node)
#define EPC 8192     // edges per chunk in binning
#define BK_SHIFT 9   // 512 nodes per bucket
#define BNODES 512
#define SCHUNK 1024  // elements per scan block
#define APAD 136     // halves per sA row: 128 + 8 pad

typedef _Float16 half8 __attribute__((ext_vector_type(8)));
typedef float f32x4 __attribute__((ext_vector_type(4)));

union U8 { uint2 u; __half2 h[2]; };

// ---- fused prep: fp32->fp16 convert | binA histogram | W fragment swizzle ----
// block ranges: [0,nconvb) convert, [nconvb,nconvb+nc) binA, rest wswz
__global__ __launch_bounds__(256) void prep_kernel(
    const float* __restrict__ x, __half* __restrict__ x16, int n8, int nconvb,
    const int* __restrict__ dst, int e, int nc, int* __restrict__ histT, int nbuck,
    const float* __restrict__ Wl, const float* __restrict__ Wr, __half* __restrict__ Wswz)
{
    __shared__ int h[BNODES];
    int bid = blockIdx.x, tid = threadIdx.x;
    if (bid < nconvb) {
        int i = bid * 256 + tid;
        if (i < n8) {
            const float4* p = reinterpret_cast<const float4*>(x + (size_t)i * 8);
            float4 a = p[0], b = p[1];
            __half2* q = reinterpret_cast<__half2*>(x16 + (size_t)i * 8);
            q[0] = __floats2half2_rn(a.x, a.y);
            q[1] = __floats2half2_rn(a.z, a.w);
            q[2] = __floats2half2_rn(b.x, b.y);
            q[3] = __floats2half2_rn(b.z, b.w);
        }
    } else if (bid < nconvb + nc) {
        int c = bid - nconvb;
        for (int i = tid; i < nbuck; i += 256) h[i] = 0;
        __syncthreads();
        int base = c * EPC;
#pragma unroll
        for (int j = 0; j < EPC / 256; ++j) {
            int i = base + j * 256 + tid;
            if (i < e) atomicAdd(&h[dst[i] >> BK_SHIFT], 1);
        }
        __syncthreads();
        for (int b = tid; b < nbuck; b += 256) histT[b * nc + c] = h[b];
    } else {
        // Wswz[L][kt][nt][lane][i]: k = kt*32 + 8*(lane>>4) + i, n = nt*16 + (lane&15)
        int idx = (bid - nconvb - nc) * 256 + tid;
        int total = 3 * 4 * 4 * 64;
        if (idx < total) {
            int lane = idx & 63;
            int nt   = (idx >> 6) & 3;
            int kt   = (idx >> 8) & 3;
            int L    = idx >> 10;
            int nn    = nt * 16 + (lane & 15);
            int kbase = kt * 32 + 8 * (lane >> 4);
            __half* o = Wswz + (size_t)idx * 8;
#pragma unroll
            for (int i = 0; i < 8; ++i) {
                int k = kbase + i;
                float v = (k < 64) ? Wl[(size_t)L * 4096 + (size_t)k * 64 + nn]
                                   : Wr[(size_t)L * 4096 + (size_t)(k - 64) * 64 + nn];
                o[i] = __float2half(v);
            }
        }
    }
}

// ---- parallel two-level exclusive scan over histT[0..tot), in place ----
__global__ __launch_bounds__(256) void scan_part_kernel(const int* __restrict__ data, int tot,
                                                        int* __restrict__ blocksum) {
    __shared__ int red[256];
    int tid = threadIdx.x;
    int base = blockIdx.x * SCHUNK + tid * 4;
    int s = 0;
#pragma unroll
    for (int j = 0; j < 4; ++j) {
        int i = base + j;
        if (i < tot) s += data[i];
    }
    red[tid] = s;
    __syncthreads();
    for (int off = 128; off > 0; off >>= 1) {
        if (tid < off) red[tid] += red[tid + off];
        __syncthreads();
    }
    if (tid == 0) blocksum[blockIdx.x] = red[0];
}

__global__ __launch_bounds__(1024) void scan_mid_kernel(int* __restrict__ blocksum, int nb) {
    __shared__ int sc[1024];
    int tid = threadIdx.x;
    int v = (tid < nb) ? blocksum[tid] : 0;
    sc[tid] = v;
    __syncthreads();
    for (int off = 1; off < 1024; off <<= 1) {
        int t = (tid >= off) ? sc[tid - off] : 0;
        __syncthreads();
        sc[tid] += t;
        __syncthreads();
    }
    if (tid < nb) blocksum[tid] = sc[tid] - v;   // exclusive
}

__global__ __launch_bounds__(256) void scan_write_kernel(int* __restrict__ data, int tot,
                                                         const int* __restrict__ blockoff) {
    __shared__ int sc[256];
    int tid = threadIdx.x;
    int base = blockIdx.x * SCHUNK + tid * 4;
    int e0 = 0, e1 = 0, e2 = 0, e3 = 0;
    if (base + 0 < tot) e0 = data[base + 0];
    if (base + 1 < tot) e1 = data[base + 1];
    if (base + 2 < tot) e2 = data[base + 2];
    if (base + 3 < tot) e3 = data[base + 3];
    int s = e0 + e1 + e2 + e3;
    sc[tid] = s;
    __syncthreads();
    for (int off = 1; off < 256; off <<= 1) {
        int t = (tid >= off) ? sc[tid - off] : 0;
        __syncthreads();
        sc[tid] += t;
        __syncthreads();
    }
    int run = blockoff[blockIdx.x] + sc[tid] - s;
    if (base + 0 < tot) data[base + 0] = run;
    if (base + 1 < tot) data[base + 1] = run + e0;
    if (base + 2 < tot) data[base + 2] = run + e0 + e1;
    if (base + 3 < tot) data[base + 3] = run + e0 + e1 + e2;
}

// Pass B: scatter packed (dstLocal<<23 | src) into bucket-grouped runs.
// src < 2^23, dstLocal < 512 with BK_SHIFT=9.
__global__ __launch_bounds__(256) void binB_kernel(const int* __restrict__ src, const int* __restrict__ dst,
                                                   int e, int nc, const int* __restrict__ offT,
                                                   int nbuck, int* __restrict__ binned) {
    __shared__ int cur[BNODES];
    int tid = threadIdx.x, c = blockIdx.x;
    for (int b = tid; b < nbuck; b += 256) cur[b] = offT[b * nc + c];
    __syncthreads();
    int base = c * EPC;
#pragma unroll
    for (int j = 0; j < EPC / 256; ++j) {
        int i = base + j * 256 + tid;
        if (i < e) {
            int d = dst[i];
            int p = atomicAdd(&cur[d >> BK_SHIFT], 1);
            binned[p] = (int)(((unsigned)(d & (BNODES - 1)) << 23) | (unsigned)src[i]);
        }
    }
}

// Per-bucket: degree hist -> LDS scan -> rowp (coalesced) -> place esrc
__global__ __launch_bounds__(BNODES) void place_kernel(const int* __restrict__ binned,
                                                       const int* __restrict__ offT, int nc,
                                                       int nbuck, int e, int n,
                                                       int* __restrict__ rowp, int* __restrict__ esrc) {
    __shared__ int deg[BNODES];
    __shared__ int sc[BNODES];
    int tid = threadIdx.x, b = blockIdx.x;
    int node0 = b << BK_SHIFT;
    int base = offT[b * nc];
    int end  = (b + 1 < nbuck) ? offT[(b + 1) * nc] : e;
    deg[tid] = 0;
    __syncthreads();
    for (int i = base + tid; i < end; i += BNODES)
        atomicAdd(&deg[(unsigned)binned[i] >> 23], 1);
    __syncthreads();
    int v = deg[tid];
    sc[tid] = v;
    __syncthreads();
    for (int off = 1; off < BNODES; off <<= 1) {
        int t = (tid >= off) ? sc[tid - off] : 0;
        __syncthreads();
        sc[tid] += t;
        __syncthreads();
    }
    int excl = sc[tid] - v;
    int node = node0 + tid;
    if (node < n) rowp[node] = base + excl;
    if (b == 0 && tid == 0) rowp[n] = e;
    deg[tid] = base + excl;   // reuse as cursor
    __syncthreads();
    for (int i = base + tid; i < end; i += BNODES) {
        int p = binned[i];
        int pos = atomicAdd(&deg[(unsigned)p >> 23], 1);
        esrc[pos] = p & 0x7FFFFF;
    }
}

// Fused layer (round-15 proven config): fp16 gather (16 lanes/node, 8B/lane,
// 8-deep MLP) -> sA[32][136] fp16 = [agg|h], then MFMA combine:
// 8 waves, wave (mtile = w>>2, nt = w&3) computes a 16x16 C tile.
__global__ __launch_bounds__(512) void sage_layer_kernel(
    const __half* __restrict__ hin16, const float* __restrict__ self32,
    const int* __restrict__ rowp, const int* __restrict__ esrc,
    const __half* __restrict__ Bfrag,     // [4kt][4nt][64][8] fp16
    const float* __restrict__ bias,
    float* __restrict__ out32, __half* __restrict__ out16,
    int n, int relu)
{
    __shared__ _Float16 sA[NPB][APAD];

    int tid = threadIdx.x;
    int grp = tid >> 4;      // node within block (0..31)
    int l   = tid & 15;      // col quad 0..15
    int node = blockIdx.x * NPB + grp;

    if (node < n) {
        if (self32) {
            float4 h4 = *reinterpret_cast<const float4*>(self32 + (size_t)node * DD + l * 4);
            U8 pk; pk.h[0] = __floats2half2_rn(h4.x, h4.y); pk.h[1] = __floats2half2_rn(h4.z, h4.w);
            *reinterpret_cast<uint2*>(&sA[grp][64 + 4 * l]) = pk.u;
        } else {
            uint2 v = *reinterpret_cast<const uint2*>(hin16 + (size_t)node * DD + l * 4);
            *reinterpret_cast<uint2*>(&sA[grp][64 + 4 * l]) = v;
        }

        int beg = rowp[node], end = rowp[node + 1];
        float ax = 0.f, ay = 0.f, az = 0.f, aw = 0.f;
        int t = beg;
        for (; t + 8 <= end; t += 8) {   // 8 independent 128B row reads in flight
            int s0 = esrc[t + 0], s1 = esrc[t + 1], s2 = esrc[t + 2], s3 = esrc[t + 3];
            int s4 = esrc[t + 4], s5 = esrc[t + 5], s6 = esrc[t + 6], s7 = esrc[t + 7];
            U8 v0, v1, v2, v3, v4, v5, v6, v7;
            v0.u = *reinterpret_cast<const uint2*>(hin16 + (size_t)s0 * DD + l * 4);
            v1.u = *reinterpret_cast<const uint2*>(hin16 + (size_t)s1 * DD + l * 4);
            v2.u = *reinterpret_cast<const uint2*>(hin16 + (size_t)s2 * DD + l * 4);
            v3.u = *reinterpret_cast<const uint2*>(hin16 + (size_t)s3 * DD + l * 4);
            v4.u = *reinterpret_cast<const uint2*>(hin16 + (size_t)s4 * DD + l * 4);
            v5.u = *reinterpret_cast<const uint2*>(hin16 + (size_t)s5 * DD + l * 4);
            v6.u = *reinterpret_cast<const uint2*>(hin16 + (size_t)s6 * DD + l * 4);
            v7.u = *reinterpret_cast<const uint2*>(hin16 + (size_t)s7 * DD + l * 4);
            float2 a0 = __half22float2(v0.h[0]), b0 = __half22float2(v0.h[1]);
            float2 a1 = __half22float2(v1.h[0]), b1 = __half22float2(v1.h[1]);
            float2 a2 = __half22float2(v2.h[0]), b2 = __half22float2(v2.h[1]);
            float2 a3 = __half22float2(v3.h[0]), b3 = __half22float2(v3.h[1]);
            float2 a4 = __half22float2(v4.h[0]), b4 = __half22float2(v4.h[1]);
            float2 a5 = __half22float2(v5.h[0]), b5 = __half22float2(v5.h[1]);
            float2 a6 = __half22float2(v6.h[0]), b6 = __half22float2(v6.h[1]);
            float2 a7 = __half22float2(v7.h[0]), b7 = __half22float2(v7.h[1]);
            ax += ((a0.x + a1.x) + (a2.x + a3.x)) + ((a4.x + a5.x) + (a6.x + a7.x));
            ay += ((a0.y + a1.y) + (a2.y + a3.y)) + ((a4.y + a5.y) + (a6.y + a7.y));
            az += ((b0.x + b1.x) + (b2.x + b3.x)) + ((b4.x + b5.x) + (b6.x + b7.x));
            aw += ((b0.y + b1.y) + (b2.y + b3.y)) + ((b4.y + b5.y) + (b6.y + b7.y));
        }
        if (t + 4 <= end) {
            int s0 = esrc[t + 0], s1 = esrc[t + 1], s2 = esrc[t + 2], s3 = esrc[t + 3];
            U8 v0, v1, v2, v3;
            v0.u = *reinterpret_cast<const uint2*>(hin16 + (size_t)s0 * DD + l * 4);
            v1.u = *reinterpret_cast<const uint2*>(hin16 + (size_t)s1 * DD + l * 4);
            v2.u = *reinterpret_cast<const uint2*>(hin16 + (size_t)s2 * DD + l * 4);
            v3.u = *reinterpret_cast<const uint2*>(hin16 + (size_t)s3 * DD + l * 4);
            float2 a0 = __half22float2(v0.h[0]), b0 = __half22float2(v0.h[1]);
            float2 a1 = __half22float2(v1.h[0]), b1 = __half22float2(v1.h[1]);
            float2 a2 = __half22float2(v2.h[0]), b2 = __half22float2(v2.h[1]);
            float2 a3 = __half22float2(v3.h[0]), b3 = __half22float2(v3.h[1]);
            ax += (a0.x + a1.x) + (a2.x + a3.x);
            ay += (a0.y + a1.y) + (a2.y + a3.y);
            az += (b0.x + b1.x) + (b2.x + b3.x);
            aw += (b0.y + b1.y) + (b2.y + b3.y);
            t += 4;
        }
        for (; t < end; ++t) {
            int s = esrc[t];
            U8 v; v.u = *reinterpret_cast<const uint2*>(hin16 + (size_t)s * DD + l * 4);
            float2 f0 = __half22float2(v.h[0]), f1 = __half22float2(v.h[1]);
            ax += f0.x; ay += f0.y; az += f1.x; aw += f1.y;
        }
        float inv = 1.0f / fmaxf((float)(end - beg), 1.0f);
        U8 pk; pk.h[0] = __floats2half2_rn(ax * inv, ay * inv);
               pk.h[1] = __floats2half2_rn(az * inv, aw * inv);
        *reinterpret_cast<uint2*>(&sA[grp][4 * l]) = pk.u;
    }
    __syncthreads();

    // MFMA combine
    int wave  = tid >> 6;
    int lane  = tid & 63;
    int mtile = wave >> 2;          // 0..1 (16 nodes each)
    int nt    = wave & 3;           // 0..3 (16 cols each)
    int arow  = mtile * 16 + (lane & 15);
    f32x4 acc = {0.f, 0.f, 0.f, 0.f};
    const half8* bfr = reinterpret_cast<const half8*>(Bfrag);
#pragma unroll
    for (int kt = 0; kt < 4; ++kt) {
        half8 a = *reinterpret_cast<const half8*>(&sA[arow][kt * 32 + 8 * (lane >> 4)]);
        half8 b = bfr[(kt * 4 + nt) * 64 + lane];
        acc = __builtin_amdgcn_mfma_f32_16x16x32_f16(a, b, acc, 0, 0, 0);
    }
    int col = nt * 16 + (lane & 15);
    float bv = bias[col];
    int rbase = blockIdx.x * NPB + mtile * 16 + (lane >> 4) * 4;
#pragma unroll
    for (int j = 0; j < 4; ++j) {
        int r = rbase + j;
        if (r < n) {
            float o = acc[j] + bv;
            if (relu) o = fmaxf(o, 0.f);
            if (out32) out32[(size_t)r * DD + col] = o;
            if (out16) out16[(size_t)r * DD + col] = __float2half(o);
        }
    }
}

extern "C" void kernel_launch(void* const* d_in, const int* in_sizes, int n_in,
                              void* d_out, int out_size, void* d_ws, size_t ws_size,
                              hipStream_t stream) {
    (void)n_in; (void)out_size; (void)ws_size;
    const float* x  = (const float*)d_in[0];
    const int*   ei = (const int*)d_in[1];
    const float* Wl = (const float*)d_in[2];
    const float* Wr = (const float*)d_in[3];
    const float* bb = (const float*)d_in[4];
    float* out = (float*)d_out;

    int n = in_sizes[0] / DD;   // 100000
    int e = in_sizes[1] / 2;    // 1600000
    const int* src = ei;
    const int* dst = ei + e;

    int nc    = (e + EPC - 1) / EPC;          // 196
    int nbuck = (n + BNODES - 1) >> BK_SHIFT; // 196
    int tot   = nbuck * nc;                   // 38,416
    int nsb   = (tot + SCHUNK - 1) / SCHUNK;  // 38

    char* cur = (char*)d_ws;
    auto alloc = [&](size_t bytes) -> void* {
        void* p = (void*)cur;
        cur += (bytes + 255) & ~(size_t)255;
        return p;
    };
    int*    histT  = (int*)alloc((size_t)tot * 4);
    int*    bsum   = (int*)alloc(1024 * 4);
    int*    binned = (int*)alloc((size_t)e * 4);
    int*    rowp   = (int*)alloc(((size_t)n + 1) * 4);
    int*    esrc   = (int*)alloc((size_t)e * 4);
    __half* x16    = (__half*)alloc((size_t)n * DD * 2);
    __half* hA16   = (__half*)alloc((size_t)n * DD * 2);
    __half* hB16   = (__half*)alloc((size_t)n * DD * 2);
    __half* Wswz   = (__half*)alloc((size_t)3 * 8192 * 2);   // 16 KB/layer

    int n8     = n * DD / 8;                  // 800,000
    int nconvb = (n8 + 255) / 256;            // 3125
    int nwswzb = (3 * 4 * 4 * 64 + 255) / 256; // 12
    prep_kernel<<<nconvb + nc + nwswzb, 256, 0, stream>>>(
        x, x16, n8, nconvb, dst, e, nc, histT, nbuck, Wl, Wr, Wswz);

    scan_part_kernel<<<nsb, 256, 0, stream>>>(histT, tot, bsum);
    scan_mid_kernel<<<1, 1024, 0, stream>>>(bsum, nsb);
    scan_write_kernel<<<nsb, 256, 0, stream>>>(histT, tot, bsum);
    binB_kernel<<<nc, 256, 0, stream>>>(src, dst, e, nc, histT, nbuck, binned);
    place_kernel<<<nbuck, BNODES, 0, stream>>>(binned, histT, nc, nbuck, e, n, rowp, esrc);

    int lb = (n + NPB - 1) / NPB;
    sage_layer_kernel<<<lb, 512, 0, stream>>>(x16,  x,       rowp, esrc, Wswz,         bb,          nullptr, hA16, n, 1);
    sage_layer_kernel<<<lb, 512, 0, stream>>>(hA16, nullptr, rowp, esrc, Wswz + 8192,  bb + DD,     nullptr, hB16, n, 1);
    sage_layer_kernel<<<lb, 512, 0, stream>>>(hB16, nullptr, rowp, esrc, Wswz + 16384, bb + 2 * DD, out,     nullptr, n, 0);
}

// Round 19
// 180.657 us; speedup vs baseline: 1.1130x; 1.0263x over previous
//
#include <hip/hip_runtime.h>
#include <hip/hip_fp16.h>

#define DD 64
#define NPB 32       // nodes per block in sage_layer (512 threads, 16 lanes/node)
#define EPC 8192     // edges per chunk in binning
#define BK_SHIFT 9   // 512 nodes per bucket
#define BNODES 512
#define SCHUNK 1024  // elements per scan block
#define APAD 136     // halves per sA row: 128 + 8 pad

typedef _Float16 half8 __attribute__((ext_vector_type(8)));
typedef float f32x4 __attribute__((ext_vector_type(4)));

union U8 { uint2 u; __half2 h[2]; };

// ---- fused prep: fp32->fp16 convert | binA histogram | W fragment swizzle ----
// block ranges: [0,nconvb) convert, [nconvb,nconvb+nc) binA, rest wswz
__global__ __launch_bounds__(256) void prep_kernel(
    const float* __restrict__ x, __half* __restrict__ x16, int n8, int nconvb,
    const int* __restrict__ dst, int e, int nc, int* __restrict__ histT, int nbuck,
    const float* __restrict__ Wl, const float* __restrict__ Wr, __half* __restrict__ Wswz)
{
    __shared__ int h[BNODES];
    int bid = blockIdx.x, tid = threadIdx.x;
    if (bid < nconvb) {
        int i = bid * 256 + tid;
        if (i < n8) {
            const float4* p = reinterpret_cast<const float4*>(x + (size_t)i * 8);
            float4 a = p[0], b = p[1];
            __half2* q = reinterpret_cast<__half2*>(x16 + (size_t)i * 8);
            q[0] = __floats2half2_rn(a.x, a.y);
            q[1] = __floats2half2_rn(a.z, a.w);
            q[2] = __floats2half2_rn(b.x, b.y);
            q[3] = __floats2half2_rn(b.z, b.w);
        }
    } else if (bid < nconvb + nc) {
        int c = bid - nconvb;
        for (int i = tid; i < nbuck; i += 256) h[i] = 0;
        __syncthreads();
        int base = c * EPC;
#pragma unroll
        for (int j = 0; j < EPC / 256; ++j) {
            int i = base + j * 256 + tid;
            if (i < e) atomicAdd(&h[dst[i] >> BK_SHIFT], 1);
        }
        __syncthreads();
        for (int b = tid; b < nbuck; b += 256) histT[b * nc + c] = h[b];
    } else {
        // Wswz[L][kt][nt][lane][i]: k = kt*32 + 8*(lane>>4) + i, n = nt*16 + (lane&15)
        int idx = (bid - nconvb - nc) * 256 + tid;
        int total = 3 * 4 * 4 * 64;
        if (idx < total) {
            int lane = idx & 63;
            int nt   = (idx >> 6) & 3;
            int kt   = (idx >> 8) & 3;
            int L    = idx >> 10;
            int nn    = nt * 16 + (lane & 15);
            int kbase = kt * 32 + 8 * (lane >> 4);
            __half* o = Wswz + (size_t)idx * 8;
#pragma unroll
            for (int i = 0; i < 8; ++i) {
                int k = kbase + i;
                float v = (k < 64) ? Wl[(size_t)L * 4096 + (size_t)k * 64 + nn]
                                   : Wr[(size_t)L * 4096 + (size_t)(k - 64) * 64 + nn];
                o[i] = __float2half(v);
            }
        }
    }
}

// ---- two-kernel exclusive scan over histT[0..tot), in place ----
__global__ __launch_bounds__(256) void scan_part_kernel(const int* __restrict__ data, int tot,
                                                        int* __restrict__ blocksum) {
    __shared__ int red[256];
    int tid = threadIdx.x;
    int base = blockIdx.x * SCHUNK + tid * 4;
    int s = 0;
#pragma unroll
    for (int j = 0; j < 4; ++j) {
        int i = base + j;
        if (i < tot) s += data[i];
    }
    red[tid] = s;
    __syncthreads();
    for (int off = 128; off > 0; off >>= 1) {
        if (tid < off) red[tid] += red[tid + off];
        __syncthreads();
    }
    if (tid == 0) blocksum[blockIdx.x] = red[0];
}

// scan_write computes its own block offset: exclusive prefix of blocksum[0..bid)
// via a single-wave shfl reduce (nsb <= 64).
__global__ __launch_bounds__(256) void scan_write_kernel(int* __restrict__ data, int tot,
                                                         const int* __restrict__ blocksum, int nsb) {
    __shared__ int sc[256];
    __shared__ int soff;
    int tid = threadIdx.x;
    if (tid < 64) {
        int v = (tid < (int)blockIdx.x && tid < nsb) ? blocksum[tid] : 0;
#pragma unroll
        for (int off = 32; off > 0; off >>= 1) v += __shfl_down(v, off);
        if (tid == 0) soff = v;
    }
    int base = blockIdx.x * SCHUNK + tid * 4;
    int e0 = 0, e1 = 0, e2 = 0, e3 = 0;
    if (base + 0 < tot) e0 = data[base + 0];
    if (base + 1 < tot) e1 = data[base + 1];
    if (base + 2 < tot) e2 = data[base + 2];
    if (base + 3 < tot) e3 = data[base + 3];
    int s = e0 + e1 + e2 + e3;
    sc[tid] = s;
    __syncthreads();
    for (int off = 1; off < 256; off <<= 1) {
        int t = (tid >= off) ? sc[tid - off] : 0;
        __syncthreads();
        sc[tid] += t;
        __syncthreads();
    }
    int run = soff + sc[tid] - s;
    if (base + 0 < tot) data[base + 0] = run;
    if (base + 1 < tot) data[base + 1] = run + e0;
    if (base + 2 < tot) data[base + 2] = run + e0 + e1;
    if (base + 3 < tot) data[base + 3] = run + e0 + e1 + e2;
}

// Pass B: scatter packed (dstLocal<<23 | src) into bucket-grouped runs.
__global__ __launch_bounds__(256) void binB_kernel(const int* __restrict__ src, const int* __restrict__ dst,
                                                   int e, int nc, const int* __restrict__ offT,
                                                   int nbuck, int* __restrict__ binned) {
    __shared__ int cur[BNODES];
    int tid = threadIdx.x, c = blockIdx.x;
    for (int b = tid; b < nbuck; b += 256) cur[b] = offT[b * nc + c];
    __syncthreads();
    int base = c * EPC;
#pragma unroll
    for (int j = 0; j < EPC / 256; ++j) {
        int i = base + j * 256 + tid;
        if (i < e) {
            int d = dst[i];
            int p = atomicAdd(&cur[d >> BK_SHIFT], 1);
            binned[p] = (int)(((unsigned)(d & (BNODES - 1)) << 23) | (unsigned)src[i]);
        }
    }
}

// Per-bucket: degree hist -> LDS scan -> rowp (coalesced) -> place esrc
__global__ __launch_bounds__(BNODES) void place_kernel(const int* __restrict__ binned,
                                                       const int* __restrict__ offT, int nc,
                                                       int nbuck, int e, int n,
                                                       int* __restrict__ rowp, int* __restrict__ esrc) {
    __shared__ int deg[BNODES];
    __shared__ int sc[BNODES];
    int tid = threadIdx.x, b = blockIdx.x;
    int node0 = b << BK_SHIFT;
    int base = offT[b * nc];
    int end  = (b + 1 < nbuck) ? offT[(b + 1) * nc] : e;
    deg[tid] = 0;
    __syncthreads();
    for (int i = base + tid; i < end; i += BNODES)
        atomicAdd(&deg[(unsigned)binned[i] >> 23], 1);
    __syncthreads();
    int v = deg[tid];
    sc[tid] = v;
    __syncthreads();
    for (int off = 1; off < BNODES; off <<= 1) {
        int t = (tid >= off) ? sc[tid - off] : 0;
        __syncthreads();
        sc[tid] += t;
        __syncthreads();
    }
    int excl = sc[tid] - v;
    int node = node0 + tid;
    if (node < n) rowp[node] = base + excl;
    if (b == 0 && tid == 0) rowp[n] = e;
    deg[tid] = base + excl;   // reuse as cursor
    __syncthreads();
    for (int i = base + tid; i < end; i += BNODES) {
        int p = binned[i];
        int pos = atomicAdd(&deg[(unsigned)p >> 23], 1);
        esrc[pos] = p & 0x7FFFFF;
    }
}

// Fused layer: fp16 gather (16 lanes/node, 8B/lane, 8-deep MLP) -> sA[32][136]
// fp16 = [agg|h], then MFMA combine (8 waves, 16x16 C tiles, K=128).
__global__ __launch_bounds__(512) void sage_layer_kernel(
    const __half* __restrict__ hin16,
    const int* __restrict__ rowp, const int* __restrict__ esrc,
    const __half* __restrict__ Bfrag,     // [4kt][4nt][64][8] fp16
    const float* __restrict__ bias,
    float* __restrict__ out32, __half* __restrict__ out16,
    int n, int relu)
{
    __shared__ _Float16 sA[NPB][APAD];

    int tid = threadIdx.x;
    int grp = tid >> 4;      // node within block (0..31)
    int l   = tid & 15;      // col quad 0..15
    int node = blockIdx.x * NPB + grp;

    if (node < n) {
        uint2 sv = *reinterpret_cast<const uint2*>(hin16 + (size_t)node * DD + l * 4);
        *reinterpret_cast<uint2*>(&sA[grp][64 + 4 * l]) = sv;

        int beg = rowp[node], end = rowp[node + 1];
        float ax = 0.f, ay = 0.f, az = 0.f, aw = 0.f;
        int t = beg;
        for (; t + 8 <= end; t += 8) {   // 8 independent 128B row reads in flight
            int s0 = esrc[t + 0], s1 = esrc[t + 1], s2 = esrc[t + 2], s3 = esrc[t + 3];
            int s4 = esrc[t + 4], s5 = esrc[t + 5], s6 = esrc[t + 6], s7 = esrc[t + 7];
            U8 v0, v1, v2, v3, v4, v5, v6, v7;
            v0.u = *reinterpret_cast<const uint2*>(hin16 + (size_t)s0 * DD + l * 4);
            v1.u = *reinterpret_cast<const uint2*>(hin16 + (size_t)s1 * DD + l * 4);
            v2.u = *reinterpret_cast<const uint2*>(hin16 + (size_t)s2 * DD + l * 4);
            v3.u = *reinterpret_cast<const uint2*>(hin16 + (size_t)s3 * DD + l * 4);
            v4.u = *reinterpret_cast<const uint2*>(hin16 + (size_t)s4 * DD + l * 4);
            v5.u = *reinterpret_cast<const uint2*>(hin16 + (size_t)s5 * DD + l * 4);
            v6.u = *reinterpret_cast<const uint2*>(hin16 + (size_t)s6 * DD + l * 4);
            v7.u = *reinterpret_cast<const uint2*>(hin16 + (size_t)s7 * DD + l * 4);
            float2 a0 = __half22float2(v0.h[0]), b0 = __half22float2(v0.h[1]);
            float2 a1 = __half22float2(v1.h[0]), b1 = __half22float2(v1.h[1]);
            float2 a2 = __half22float2(v2.h[0]), b2 = __half22float2(v2.h[1]);
            float2 a3 = __half22float2(v3.h[0]), b3 = __half22float2(v3.h[1]);
            float2 a4 = __half22float2(v4.h[0]), b4 = __half22float2(v4.h[1]);
            float2 a5 = __half22float2(v5.h[0]), b5 = __half22float2(v5.h[1]);
            float2 a6 = __half22float2(v6.h[0]), b6 = __half22float2(v6.h[1]);
            float2 a7 = __half22float2(v7.h[0]), b7 = __half22float2(v7.h[1]);
            ax += ((a0.x + a1.x) + (a2.x + a3.x)) + ((a4.x + a5.x) + (a6.x + a7.x));
            ay += ((a0.y + a1.y) + (a2.y + a3.y)) + ((a4.y + a5.y) + (a6.y + a7.y));
            az += ((b0.x + b1.x) + (b2.x + b3.x)) + ((b4.x + b5.x) + (b6.x + b7.x));
            aw += ((b0.y + b1.y) + (b2.y + b3.y)) + ((b4.y + b5.y) + (b6.y + b7.y));
        }
        if (t + 4 <= end) {
            int s0 = esrc[t + 0], s1 = esrc[t + 1], s2 = esrc[t + 2], s3 = esrc[t + 3];
            U8 v0, v1, v2, v3;
            v0.u = *reinterpret_cast<const uint2*>(hin16 + (size_t)s0 * DD + l * 4);
            v1.u = *reinterpret_cast<const uint2*>(hin16 + (size_t)s1 * DD + l * 4);
            v2.u = *reinterpret_cast<const uint2*>(hin16 + (size_t)s2 * DD + l * 4);
            v3.u = *reinterpret_cast<const uint2*>(hin16 + (size_t)s3 * DD + l * 4);
            float2 a0 = __half22float2(v0.h[0]), b0 = __half22float2(v0.h[1]);
            float2 a1 = __half22float2(v1.h[0]), b1 = __half22float2(v1.h[1]);
            float2 a2 = __half22float2(v2.h[0]), b2 = __half22float2(v2.h[1]);
            float2 a3 = __half22float2(v3.h[0]), b3 = __half22float2(v3.h[1]);
            ax += (a0.x + a1.x) + (a2.x + a3.x);
            ay += (a0.y + a1.y) + (a2.y + a3.y);
            az += (b0.x + b1.x) + (b2.x + b3.x);
            aw += (b0.y + b1.y) + (b2.y + b3.y);
            t += 4;
        }
        for (; t < end; ++t) {
            int s = esrc[t];
            U8 v; v.u = *reinterpret_cast<const uint2*>(hin16 + (size_t)s * DD + l * 4);
            float2 f0 = __half22float2(v.h[0]), f1 = __half22float2(v.h[1]);
            ax += f0.x; ay += f0.y; az += f1.x; aw += f1.y;
        }
        float inv = 1.0f / fmaxf((float)(end - beg), 1.0f);
        U8 pk; pk.h[0] = __floats2half2_rn(ax * inv, ay * inv);
               pk.h[1] = __floats2half2_rn(az * inv, aw * inv);
        *reinterpret_cast<uint2*>(&sA[grp][4 * l]) = pk.u;
    }
    __syncthreads();

    // MFMA combine
    int wave  = tid >> 6;
    int lane  = tid & 63;
    int mtile = wave >> 2;          // 0..1 (16 nodes each)
    int nt    = wave & 3;           // 0..3 (16 cols each)
    int arow  = mtile * 16 + (lane & 15);
    f32x4 acc = {0.f, 0.f, 0.f, 0.f};
    const half8* bfr = reinterpret_cast<const half8*>(Bfrag);
#pragma unroll
    for (int kt = 0; kt < 4; ++kt) {
        half8 a = *reinterpret_cast<const half8*>(&sA[arow][kt * 32 + 8 * (lane >> 4)]);
        half8 b = bfr[(kt * 4 + nt) * 64 + lane];
        acc = __builtin_amdgcn_mfma_f32_16x16x32_f16(a, b, acc, 0, 0, 0);
    }
    int col = nt * 16 + (lane & 15);
    float bv = bias[col];
    int rbase = blockIdx.x * NPB + mtile * 16 + (lane >> 4) * 4;
#pragma unroll
    for (int j = 0; j < 4; ++j) {
        int r = rbase + j;
        if (r < n) {
            float o = acc[j] + bv;
            if (relu) o = fmaxf(o, 0.f);
            if (out32) out32[(size_t)r * DD + col] = o;
            if (out16) out16[(size_t)r * DD + col] = __float2half(o);
        }
    }
}

extern "C" void kernel_launch(void* const* d_in, const int* in_sizes, int n_in,
                              void* d_out, int out_size, void* d_ws, size_t ws_size,
                              hipStream_t stream) {
    (void)n_in; (void)out_size; (void)ws_size;
    const float* x  = (const float*)d_in[0];
    const int*   ei = (const int*)d_in[1];
    const float* Wl = (const float*)d_in[2];
    const float* Wr = (const float*)d_in[3];
    const float* bb = (const float*)d_in[4];
    float* out = (float*)d_out;

    int n = in_sizes[0] / DD;   // 100000
    int e = in_sizes[1] / 2;    // 1600000
    const int* src = ei;
    const int* dst = ei + e;

    int nc    = (e + EPC - 1) / EPC;          // 196
    int nbuck = (n + BNODES - 1) >> BK_SHIFT; // 196
    int tot   = nbuck * nc;                   // 38,416
    int nsb   = (tot + SCHUNK - 1) / SCHUNK;  // 38 (must stay <= 64 for scan_write)

    char* cur = (char*)d_ws;
    auto alloc = [&](size_t bytes) -> void* {
        void* p = (void*)cur;
        cur += (bytes + 255) & ~(size_t)255;
        return p;
    };
    int*    histT  = (int*)alloc((size_t)tot * 4);
    int*    bsum   = (int*)alloc(1024 * 4);
    int*    binned = (int*)alloc((size_t)e * 4);
    int*    rowp   = (int*)alloc(((size_t)n + 1) * 4);
    int*    esrc   = (int*)alloc((size_t)e * 4);
    __half* x16    = (__half*)alloc((size_t)n * DD * 2);
    __half* hA16   = (__half*)alloc((size_t)n * DD * 2);
    __half* hB16   = (__half*)alloc((size_t)n * DD * 2);
    __half* Wswz   = (__half*)alloc((size_t)3 * 8192 * 2);   // 16 KB/layer

    int n8     = n * DD / 8;                  // 800,000
    int nconvb = (n8 + 255) / 256;            // 3125
    int nwswzb = (3 * 4 * 4 * 64 + 255) / 256; // 12
    prep_kernel<<<nconvb + nc + nwswzb, 256, 0, stream>>>(
        x, x16, n8, nconvb, dst, e, nc, histT, nbuck, Wl, Wr, Wswz);

    scan_part_kernel<<<nsb, 256, 0, stream>>>(histT, tot, bsum);
    scan_write_kernel<<<nsb, 256, 0, stream>>>(histT, tot, bsum, nsb);
    binB_kernel<<<nc, 256, 0, stream>>>(src, dst, e, nc, histT, nbuck, binned);
    place_kernel<<<nbuck, BNODES, 0, stream>>>(binned, histT, nc, nbuck, e, n, rowp, esrc);

    int lb = (n + NPB - 1) / NPB;
    sage_layer_kernel<<<lb, 512, 0, stream>>>(x16,  rowp, esrc, Wswz,         bb,          nullptr, hA16, n, 1);
    sage_layer_kernel<<<lb, 512, 0, stream>>>(hA16, rowp, esrc, Wswz + 8192,  bb + DD,     nullptr, hB16, n, 1);
    sage_layer_kernel<<<lb, 512, 0, stream>>>(hB16, rowp, esrc, Wswz + 16384, bb + 2 * DD, out,     nullptr, n, 0);
}